// Round 1
// baseline (3175.738 us; speedup 1.0000x reference)
//
#include <hip/hip_runtime.h>
#include <math.h>

// TransPhormer equivariant graph attention, fp32 reference-accurate version.
// N=10000, E=160000, MUL0=64, MUL1=32, M0=32, M1=16, H=8, NB=16
// q/kv per-head dim = M0 + 3*M1 = 80.

constexpr float EPSV        = 1e-5f;
constexpr float INV_SQRT3   = 0.5773502691896258f;
constexpr float INV_SQRT2   = 0.7071067811865476f;
constexpr float INV_SQRT32  = 0.17677669529663687f;
constexpr float INV_SQRT48  = 0.14433756729740643f;
constexpr float INV_SQRT128 = 0.08838834764831845f;
constexpr float SCALE_ATT   = 0.14433756729740643f; // 1/sqrt(48)

__device__ __forceinline__ float wsum64(float v) {
#pragma unroll
  for (int m = 1; m < 64; m <<= 1) v += __shfl_xor(v, m);
  return v;
}

// monotonic float<->uint mapping for atomicMax on floats
__device__ __forceinline__ unsigned fmap(float f) {
  unsigned b = __float_as_uint(f);
  return (b & 0x80000000u) ? ~b : (b | 0x80000000u);
}
__device__ __forceinline__ float funmap(unsigned s) {
  unsigned b = (s & 0x80000000u) ? (s & 0x7FFFFFFFu) : ~s;
  return __uint_as_float(b);
}

__global__ void init_ws_k(float* __restrict__ msg, float* __restrict__ zbuf,
                          unsigned* __restrict__ smax, int N) {
  int idx = blockIdx.x * blockDim.x + threadIdx.x;
  if (idx < N * 640) msg[idx] = 0.f;
  if (idx < N * 8) { zbuf[idx] = 0.f; smax[idx] = 0x007FFFFFu; } // fmap(-inf)
}

// ---------------- node pre: norm + Q + src/dst projections ----------------
__global__ __launch_bounds__(64) void node_pre(
    const float* __restrict__ node, const float* __restrict__ gamma0,
    const float* __restrict__ gamma1,
    const float* __restrict__ Wq0, const float* __restrict__ Wq1,
    const float* __restrict__ Wsrc0, const float* __restrict__ Wsrc1,
    const float* __restrict__ Wdst0, const float* __restrict__ Wdst1,
    float* __restrict__ qbuf, float* __restrict__ sbuf, float* __restrict__ dbuf,
    int N) {
  int nidx = blockIdx.x;
  if (nidx >= N) return;
  int lane = threadIdx.x;
  __shared__ float h[160];
  const float* nrow = node + (size_t)nidx * 160;

  // h0: layernorm over 64 scalar channels
  float v0 = nrow[lane];
  float mu = wsum64(v0) * (1.0f / 64.0f);
  float dv = v0 - mu;
  float var = wsum64(dv * dv) * (1.0f / 64.0f);
  float rs0 = rsqrtf(var + EPSV);
  h[lane] = dv * rs0 * gamma0[lane];

  // h1: equivariant norm over 32 vector channels
  float a = nrow[64 + lane];
  float b = (lane < 32) ? nrow[128 + lane] : 0.0f;
  float vn = wsum64(a * a + b * b) * (1.0f / 32.0f);
  float rs1 = rsqrtf(vn + EPSV);
  h[64 + lane] = a * rs1 * gamma1[lane / 3];
  if (lane < 32) h[128 + lane] = b * rs1 * gamma1[(64 + lane) / 3];
  __syncthreads();

  // q: (8 heads, 80 dims): m<32 from Wq0, m>=32 from Wq1 (t,c)
  float* qrow = qbuf + (size_t)nidx * 640;
  for (int i = lane; i < 640; i += 64) {
    int hh = i / 80, m = i % 80;
    float acc = 0.f, val;
    if (m < 32) {
      int col = hh * 32 + m;
      for (int k = 0; k < 64; k++) acc += h[k] * Wq0[k * 256 + col];
      val = acc * 0.125f;
    } else {
      int mm = m - 32; int t = mm / 3, c = mm - t * 3;
      int col = hh * 16 + t;
      for (int u = 0; u < 32; u++) acc += h[64 + u * 3 + c] * Wq1[u * 128 + col];
      val = acc * INV_SQRT32;
    }
    qrow[i] = val;
  }

  // s / d: 80 dims each (32 scalar + 16x3 vector)
  for (int i = lane; i < 160; i += 64) {
    int which = i / 80;   // 0 = src proj, 1 = dst proj
    int j = i % 80;
    const float* W0 = which ? Wdst0 : Wsrc0;
    const float* W1 = which ? Wdst1 : Wsrc1;
    float acc = 0.f, val;
    if (j < 32) {
      for (int k = 0; k < 64; k++) acc += h[k] * W0[k * 32 + j];
      val = acc * 0.125f;
    } else {
      int jj = j - 32; int v = jj / 3, c = jj - v * 3;
      for (int u = 0; u < 32; u++) acc += h[64 + u * 3 + c] * W1[u * 16 + v];
      val = acc * INV_SQRT32;
    }
    float* obuf = which ? dbuf : sbuf;
    obuf[(size_t)nidx * 80 + j] = val;
  }
}

// ---------------- shared per-edge tensor-product build (LDS) ----------------
__device__ __forceinline__ void build_cp(
    int e, int src, int dst, int lane,
    const float* __restrict__ rbf, const float* __restrict__ rsh,
    const float* __restrict__ W_rbf,
    const float* __restrict__ sbuf, const float* __restrict__ dbuf,
    float* w, float* x, float* cp0, float* cp1) {
  // w = rbf @ W_rbf  (112)
  const float* rrow = rbf + (size_t)e * 16;
  for (int j = lane; j < 112; j += 64) {
    float acc = 0.f;
#pragma unroll
    for (int k = 0; k < 16; k++) acc += rrow[k] * W_rbf[k * 112 + j];
    w[j] = acc;
  }
  // x = s[src] + d[dst]  (80)
  const float* srow = sbuf + (size_t)src * 80;
  const float* drow = dbuf + (size_t)dst * 80;
  for (int j = lane; j < 80; j += 64) x[j] = srow[j] + drow[j];
  __syncthreads();

  float y0 = rsh[(size_t)e * 4 + 0];
  float ya = rsh[(size_t)e * 4 + 1];
  float yb = rsh[(size_t)e * 4 + 2];
  float yc = rsh[(size_t)e * 4 + 3];

  // cp0 (48): [w000*x0*y0 (32) | w110*(x1.y1)/sqrt3 (16)]
  if (lane < 48) {
    float v;
    if (lane < 32) v = w[lane] * x[lane] * y0;
    else {
      int u = lane - 32;
      float dp = x[32 + u * 3] * ya + x[32 + u * 3 + 1] * yb + x[32 + u * 3 + 2] * yc;
      v = w[32 + u] * dp * INV_SQRT3;
    }
    cp0[lane] = v;
  }
  // cp1 (64 x 3): [w011*x0*y1 (32) | w101*x1*y0 (16) | w111*cross(x1,y1)/sqrt2 (16)]
  {
    int u = lane;
    float c0, c1, c2;
    if (u < 32) {
      float aw = w[48 + u] * x[u];
      c0 = aw * ya; c1 = aw * yb; c2 = aw * yc;
    } else if (u < 48) {
      int t = u - 32; float ww = w[80 + t] * y0;
      c0 = ww * x[32 + t * 3]; c1 = ww * x[32 + t * 3 + 1]; c2 = ww * x[32 + t * 3 + 2];
    } else {
      int t = u - 48;
      float x0_ = x[32 + t * 3], x1_ = x[32 + t * 3 + 1], x2_ = x[32 + t * 3 + 2];
      float ww = w[96 + t] * INV_SQRT2;
      c0 = ww * (x1_ * yc - x2_ * yb);
      c1 = ww * (x2_ * ya - x0_ * yc);
      c2 = ww * (x0_ * yb - x1_ * ya);
    }
    cp1[u * 3] = c0; cp1[u * 3 + 1] = c1; cp1[u * 3 + 2] = c2;
  }
  __syncthreads();
}

// ---------------- edge pass A: key half + logits + segment max ----------------
__global__ __launch_bounds__(256) void edge_key(
    const float* __restrict__ rbf, const float* __restrict__ rsh,
    const int* __restrict__ edge_index,
    const float* __restrict__ W_rbf, const float* __restrict__ Wkv0,
    const float* __restrict__ Wkv1,
    const float* __restrict__ qbuf, const float* __restrict__ sbuf,
    const float* __restrict__ dbuf,
    float* __restrict__ logits, unsigned* __restrict__ smax, int E) {
  int wave = threadIdx.x >> 6;
  int lane = threadIdx.x & 63;
  int eraw = blockIdx.x * 4 + wave;
  int e = min(eraw, E - 1);
  int src = edge_index[e];
  int dst = edge_index[(size_t)E + e];

  __shared__ float lw[4][112], lx[4][80], lcp0[4][48], lcp1[4][192];
  build_cp(e, src, dst, lane, rbf, rsh, W_rbf, sbuf, dbuf,
           lw[wave], lx[wave], lcp0[wave], lcp1[wave]);
  const float* cp0 = lcp0[wave];
  const float* cp1 = lcp1[wave];

  int hh = lane >> 3, r = lane & 7;
  const float* qrow = qbuf + (size_t)src * 640 + hh * 80;
  float lacc = 0.f;
  for (int it = 0; it < 10; ++it) {
    int m = r + it * 8;
    float kv;
    if (m < 32) {
      int col = hh * 32 + m;
      float acc = 0.f;
      for (int k = 0; k < 48; k++) acc += cp0[k] * Wkv0[k * 512 + col];
      kv = acc * INV_SQRT48;
    } else {
      int mm = m - 32; int t = mm / 3, c = mm - t * 3;
      int col = hh * 16 + t;
      float acc = 0.f;
      for (int u = 0; u < 64; u++) acc += cp1[u * 3 + c] * Wkv1[u * 256 + col];
      kv = acc * 0.125f;
    }
    lacc += qrow[m] * kv;
  }
  lacc += __shfl_xor(lacc, 1);
  lacc += __shfl_xor(lacc, 2);
  lacc += __shfl_xor(lacc, 4);
  if (r == 0 && eraw < E) {
    float lg = lacc * SCALE_ATT;
    logits[(size_t)e * 8 + hh] = lg;
    atomicMax(&smax[(size_t)dst * 8 + hh], fmap(lg));
  }
}

// ---------------- edge pass B: value half + weighted scatter ----------------
__global__ __launch_bounds__(256) void edge_val(
    const float* __restrict__ rbf, const float* __restrict__ rsh,
    const int* __restrict__ edge_index,
    const float* __restrict__ W_rbf, const float* __restrict__ Wkv0,
    const float* __restrict__ Wkv1,
    const float* __restrict__ sbuf, const float* __restrict__ dbuf,
    const float* __restrict__ logits, const unsigned* __restrict__ smax,
    float* __restrict__ zbuf, float* __restrict__ msg, int E) {
  int wave = threadIdx.x >> 6;
  int lane = threadIdx.x & 63;
  int eraw = blockIdx.x * 4 + wave;
  int e = min(eraw, E - 1);
  int src = edge_index[e];
  int dst = edge_index[(size_t)E + e];

  __shared__ float lw[4][112], lx[4][80], lcp0[4][48], lcp1[4][192];
  build_cp(e, src, dst, lane, rbf, rsh, W_rbf, sbuf, dbuf,
           lw[wave], lx[wave], lcp0[wave], lcp1[wave]);
  const float* cp0 = lcp0[wave];
  const float* cp1 = lcp1[wave];

  int hh = lane >> 3, r = lane & 7;
  float lg = logits[(size_t)e * 8 + hh];
  float mx = funmap(smax[(size_t)dst * 8 + hh]);
  float aa = expf(lg - mx);

  if (r == 0 && eraw < E) atomicAdd(&zbuf[(size_t)dst * 8 + hh], aa);

  for (int it = 0; it < 10; ++it) {
    int m = r + it * 8;
    float vv;
    if (m < 32) {
      int col = 256 + hh * 32 + m;
      float acc = 0.f;
      for (int k = 0; k < 48; k++) acc += cp0[k] * Wkv0[k * 512 + col];
      vv = acc * INV_SQRT48;
    } else {
      int mm = m - 32; int t = mm / 3, c = mm - t * 3;
      int col = 128 + hh * 16 + t;
      float acc = 0.f;
      for (int u = 0; u < 64; u++) acc += cp1[u * 3 + c] * Wkv1[u * 256 + col];
      vv = acc * 0.125f;
    }
    if (eraw < E) atomicAdd(&msg[(size_t)dst * 640 + hh * 80 + m], aa * vv);
  }
}

// ---------------- node out: normalize + output projection + residual ----------------
__global__ __launch_bounds__(64) void node_out(
    const float* __restrict__ node, const float* __restrict__ msg,
    const float* __restrict__ zbuf,
    const float* __restrict__ Wmsg0, const float* __restrict__ Wmsg1,
    float* __restrict__ out, int N) {
  int nidx = blockIdx.x;
  if (nidx >= N) return;
  int lane = threadIdx.x;
  __shared__ float ml[640];
  for (int i = lane; i < 640; i += 64) {
    int hh = i / 80;
    ml[i] = msg[(size_t)nidx * 640 + i] / (zbuf[(size_t)nidx * 8 + hh] + 1e-16f);
  }
  __syncthreads();
  const float* nrow = node + (size_t)nidx * 160;
  float* orow = out + (size_t)nidx * 160;
  // o0: 64 outputs, dot over 256 (m0: j = h*32+m)
  {
    float acc = 0.f;
    for (int j = 0; j < 256; j++) {
      int hh = j >> 5, m = j & 31;
      acc += ml[hh * 80 + m] * Wmsg0[j * 64 + lane];
    }
    orow[lane] = nrow[lane] + acc * 0.0625f;
  }
  // o1: 96 outputs (v,c), dot over 128 (m1: p = h*16+t)
  for (int i = lane; i < 96; i += 64) {
    int v = i / 3, c = i - v * 3;
    float acc = 0.f;
    for (int p = 0; p < 128; p++) {
      int hh = p >> 4, t = p & 15;
      acc += ml[hh * 80 + 32 + t * 3 + c] * Wmsg1[p * 32 + v];
    }
    orow[64 + i] = nrow[64 + i] + acc * INV_SQRT128;
  }
}

extern "C" void kernel_launch(void* const* d_in, const int* in_sizes, int n_in,
                              void* d_out, int out_size, void* d_ws, size_t ws_size,
                              hipStream_t stream) {
  (void)n_in; (void)out_size; (void)ws_size;
  const float* node   = (const float*)d_in[0];
  const float* rbf    = (const float*)d_in[1];
  const float* rsh    = (const float*)d_in[2];
  const int*   eidx   = (const int*)d_in[3];
  const float* gamma0 = (const float*)d_in[4];
  const float* gamma1 = (const float*)d_in[5];
  const float* Wq0    = (const float*)d_in[6];
  const float* Wq1    = (const float*)d_in[7];
  const float* Wsrc0  = (const float*)d_in[8];
  const float* Wsrc1  = (const float*)d_in[9];
  const float* Wdst0  = (const float*)d_in[10];
  const float* Wdst1  = (const float*)d_in[11];
  const float* W_rbf  = (const float*)d_in[12];
  const float* Wkv0   = (const float*)d_in[13];
  const float* Wkv1   = (const float*)d_in[14];
  const float* Wmsg0  = (const float*)d_in[15];
  const float* Wmsg1  = (const float*)d_in[16];
  float* out = (float*)d_out;

  int N = in_sizes[0] / 160;
  int E = in_sizes[3] / 2;

  float* qbuf   = (float*)d_ws;                 // N*640
  float* sbuf   = qbuf + (size_t)N * 640;       // N*80
  float* dbuf   = sbuf + (size_t)N * 80;        // N*80
  float* logits = dbuf + (size_t)N * 80;        // E*8
  unsigned* smax = (unsigned*)(logits + (size_t)E * 8);  // N*8
  float* zbuf   = (float*)(smax + (size_t)N * 8);        // N*8
  float* msg    = zbuf + (size_t)N * 8;         // N*640

  hipLaunchKernelGGL(init_ws_k, dim3((N * 640 + 255) / 256), dim3(256), 0, stream,
                     msg, zbuf, smax, N);
  hipLaunchKernelGGL(node_pre, dim3(N), dim3(64), 0, stream,
                     node, gamma0, gamma1, Wq0, Wq1, Wsrc0, Wsrc1, Wdst0, Wdst1,
                     qbuf, sbuf, dbuf, N);
  hipLaunchKernelGGL(edge_key, dim3((E + 3) / 4), dim3(256), 0, stream,
                     rbf, rsh, eidx, W_rbf, Wkv0, Wkv1, qbuf, sbuf, dbuf,
                     logits, smax, E);
  hipLaunchKernelGGL(edge_val, dim3((E + 3) / 4), dim3(256), 0, stream,
                     rbf, rsh, eidx, W_rbf, Wkv0, Wkv1, sbuf, dbuf,
                     logits, smax, zbuf, msg, E);
  hipLaunchKernelGGL(node_out, dim3(N), dim3(64), 0, stream,
                     node, msg, zbuf, Wmsg0, Wmsg1, out, N);
}

// Round 2
// 1113.928 us; speedup vs baseline: 2.8509x; 2.8509x over previous
//
#include <hip/hip_runtime.h>
#include <math.h>

// TransPhormer equivariant graph attention — restructured:
//  - factored logits: logit[e,h] = <qk[src][h][240], cp[e][240]> (no per-edge key GEMM)
//  - counting-sort edges by dst; per-node gather aggregation of a*cp in registers
//    (no fp32 atomics, no E x 640 value buffer)
//  - value GEMM + softmax-normalize + output projection fused per node
// N=10000, E=160000, MUL0=64, MUL1=32, M0=32, M1=16, H=8, NB=16, head dim 80
// cp layout (240): [0,48) = cp0 ; [48+u*3+c] = cp1[u][c] (u<64, c<3)

constexpr float EPSV        = 1e-5f;
constexpr float INV_SQRT3   = 0.5773502691896258f;
constexpr float INV_SQRT2   = 0.7071067811865476f;
constexpr float INV_SQRT32  = 0.17677669529663687f;
constexpr float INV_SQRT48  = 0.14433756729740643f;
constexpr float INV_SQRT128 = 0.08838834764831845f;
constexpr float SCALE_ATT   = 0.14433756729740643f; // 1/sqrt(48)

__device__ __forceinline__ float wsum64(float v) {
#pragma unroll
  for (int m = 1; m < 64; m <<= 1) v += __shfl_xor(v, m);
  return v;
}

// ---------------- init: zero the degree histogram ----------------
__global__ void init_count(unsigned* __restrict__ count, int N) {
  int i = blockIdx.x * blockDim.x + threadIdx.x;
  if (i < N) count[i] = 0u;
}

// ---------------- node pre: norm + src/dst proj + factored qk ----------------
__global__ __launch_bounds__(64) void node_pre(
    const float* __restrict__ node, const float* __restrict__ gamma0,
    const float* __restrict__ gamma1,
    const float* __restrict__ Wq0, const float* __restrict__ Wq1,
    const float* __restrict__ Wsrc0, const float* __restrict__ Wsrc1,
    const float* __restrict__ Wdst0, const float* __restrict__ Wdst1,
    const float* __restrict__ Wkv0, const float* __restrict__ Wkv1,
    float* __restrict__ qkbuf, float* __restrict__ sbuf, float* __restrict__ dbuf,
    int N) {
  int nidx = blockIdx.x;
  if (nidx >= N) return;
  int lane = threadIdx.x;
  __shared__ float h[160];
  __shared__ float qL[640];
  const float* nrow = node + (size_t)nidx * 160;

  // h0: layernorm over 64 scalar channels
  float v0 = nrow[lane];
  float mu = wsum64(v0) * (1.0f / 64.0f);
  float dv = v0 - mu;
  float var = wsum64(dv * dv) * (1.0f / 64.0f);
  float rs0 = rsqrtf(var + EPSV);
  h[lane] = dv * rs0 * gamma0[lane];

  // h1: equivariant norm over 32 vector channels
  float a = nrow[64 + lane];
  float b = (lane < 32) ? nrow[128 + lane] : 0.0f;
  float vn = wsum64(a * a + b * b) * (1.0f / 32.0f);
  float rs1 = rsqrtf(vn + EPSV);
  h[64 + lane] = a * rs1 * gamma1[lane / 3];
  if (lane < 32) h[128 + lane] = b * rs1 * gamma1[(64 + lane) / 3];
  __syncthreads();

  // q into LDS: (8 heads, 80 dims)
  for (int i = lane; i < 640; i += 64) {
    int hh = i / 80, m = i % 80;
    float acc = 0.f, val;
    if (m < 32) {
      int col = hh * 32 + m;
      for (int k = 0; k < 64; k++) acc += h[k] * Wq0[k * 256 + col];
      val = acc * 0.125f;
    } else {
      int mm = m - 32; int t = mm / 3, c = mm - t * 3;
      int col = hh * 16 + t;
      for (int u = 0; u < 32; u++) acc += h[64 + u * 3 + c] * Wq1[u * 128 + col];
      val = acc * INV_SQRT32;
    }
    qL[i] = val;
  }

  // s / d projections: 80 dims each
  for (int i = lane; i < 160; i += 64) {
    int which = i / 80;
    int j = i % 80;
    const float* W0 = which ? Wdst0 : Wsrc0;
    const float* W1 = which ? Wdst1 : Wsrc1;
    float acc = 0.f, val;
    if (j < 32) {
      for (int k = 0; k < 64; k++) acc += h[k] * W0[k * 32 + j];
      val = acc * 0.125f;
    } else {
      int jj = j - 32; int v = jj / 3, c = jj - v * 3;
      for (int u = 0; u < 32; u++) acc += h[64 + u * 3 + c] * W1[u * 16 + v];
      val = acc * INV_SQRT32;
    }
    float* obuf = which ? dbuf : sbuf;
    obuf[(size_t)nidx * 80 + j] = val;
  }
  __syncthreads();

  // factored key vectors: qk[n][h][240]
  //  j<48:  A[h][k] = inv_sqrt48 * sum_m q[h][m] * Wkv0[k][h*32+m]
  //  j>=48: B[h][u][c] = 0.125  * sum_t q[h][32+t*3+c] * Wkv1[u][h*16+t]
  float* qkrow = qkbuf + (size_t)nidx * 1920;
#pragma unroll
  for (int it = 0; it < 30; ++it) {
    int i = it * 64 + lane;
    int hh = i / 240, j = i % 240;
    float acc = 0.f, val;
    if (j < 48) {
      const float* w = Wkv0 + (size_t)j * 512 + hh * 32;
      const float* q = qL + hh * 80;
#pragma unroll
      for (int m = 0; m < 32; m++) acc += q[m] * w[m];
      val = acc * INV_SQRT48;
    } else {
      int jj = j - 48; int u = jj / 3, c = jj - u * 3;
      const float* w = Wkv1 + (size_t)u * 256 + hh * 16;
      const float* q = qL + hh * 80 + 32 + c;
#pragma unroll
      for (int t = 0; t < 16; t++) acc += q[t * 3] * w[t];
      val = acc * 0.125f;
    }
    qkrow[i] = val;
  }
}

// ---------------- sort by dst: histogram / scan / scatter ----------------
__global__ void k_hist(const int* __restrict__ edge_index, unsigned* __restrict__ count,
                       int E) {
  int e = blockIdx.x * blockDim.x + threadIdx.x;
  if (e < E) atomicAdd(&count[edge_index[(size_t)E + e]], 1u);
}

__global__ __launch_bounds__(256) void k_scan(const unsigned* __restrict__ count,
                                              unsigned* __restrict__ offs,
                                              unsigned* __restrict__ cursor, int N) {
  __shared__ unsigned buf[256];
  __shared__ unsigned carry;
  if (threadIdx.x == 0) carry = 0u;
  __syncthreads();
  for (int base = 0; base < N; base += 256) {
    int i = base + threadIdx.x;
    unsigned v = (i < N) ? count[i] : 0u;
    buf[threadIdx.x] = v;
    __syncthreads();
    for (int off = 1; off < 256; off <<= 1) {
      unsigned t = (threadIdx.x >= (unsigned)off) ? buf[threadIdx.x - off] : 0u;
      __syncthreads();
      buf[threadIdx.x] += t;
      __syncthreads();
    }
    unsigned excl = buf[threadIdx.x] - v + carry;
    if (i < N) { offs[i] = excl; cursor[i] = excl; }
    __syncthreads();
    if (threadIdx.x == 255) carry += buf[255];
    __syncthreads();
  }
  if (threadIdx.x == 0) offs[N] = carry;
}

__global__ void k_scatter(const int* __restrict__ edge_index, unsigned* __restrict__ cursor,
                          unsigned* __restrict__ sorted, int E) {
  int e = blockIdx.x * blockDim.x + threadIdx.x;
  if (e < E) {
    unsigned pos = atomicAdd(&cursor[edge_index[(size_t)E + e]], 1u);
    sorted[pos] = (unsigned)e;
  }
}

// ---------------- per-edge tensor product build into LDS cp[240] ----------------
__device__ __forceinline__ void build_cp(
    int e, int lane,
    const float* __restrict__ rbf, const float* __restrict__ rsh,
    const float* __restrict__ W_rbf,
    const float* __restrict__ x,   // x = s[src]+d[dst], LDS, 80
    float* __restrict__ w,         // LDS 112 scratch
    float* __restrict__ cp) {      // LDS 240 out
  const float* rrow = rbf + (size_t)e * 16;
  for (int j = lane; j < 112; j += 64) {
    float acc = 0.f;
#pragma unroll
    for (int k = 0; k < 16; k++) acc += rrow[k] * W_rbf[k * 112 + j];
    w[j] = acc;
  }
  __syncthreads();

  float y0 = rsh[(size_t)e * 4 + 0];
  float ya = rsh[(size_t)e * 4 + 1];
  float yb = rsh[(size_t)e * 4 + 2];
  float yc = rsh[(size_t)e * 4 + 3];

  if (lane < 48) {
    float v;
    if (lane < 32) v = w[lane] * x[lane] * y0;
    else {
      int u = lane - 32;
      float dp = x[32 + u * 3] * ya + x[32 + u * 3 + 1] * yb + x[32 + u * 3 + 2] * yc;
      v = w[32 + u] * dp * INV_SQRT3;
    }
    cp[lane] = v;
  }
  {
    int u = lane;
    float c0, c1, c2;
    if (u < 32) {
      float aw = w[48 + u] * x[u];
      c0 = aw * ya; c1 = aw * yb; c2 = aw * yc;
    } else if (u < 48) {
      int t = u - 32; float ww = w[80 + t] * y0;
      c0 = ww * x[32 + t * 3]; c1 = ww * x[32 + t * 3 + 1]; c2 = ww * x[32 + t * 3 + 2];
    } else {
      int t = u - 48;
      float x0_ = x[32 + t * 3], x1_ = x[32 + t * 3 + 1], x2_ = x[32 + t * 3 + 2];
      float ww = w[96 + t] * INV_SQRT2;
      c0 = ww * (x1_ * yc - x2_ * yb);
      c1 = ww * (x2_ * ya - x0_ * yc);
      c2 = ww * (x0_ * yb - x1_ * ya);
    }
    cp[48 + u * 3]     = c0;
    cp[48 + u * 3 + 1] = c1;
    cp[48 + u * 3 + 2] = c2;
  }
  __syncthreads();
}

// ---------------- edge pass: logits via factored qk dot ----------------
__global__ __launch_bounds__(256) void edge_logit(
    const float* __restrict__ rbf, const float* __restrict__ rsh,
    const int* __restrict__ edge_index,
    const float* __restrict__ W_rbf,
    const float* __restrict__ qkbuf, const float* __restrict__ sbuf,
    const float* __restrict__ dbuf,
    float* __restrict__ logits, int E) {
  int wave = threadIdx.x >> 6;
  int lane = threadIdx.x & 63;
  int eraw = blockIdx.x * 4 + wave;
  int e = min(eraw, E - 1);
  int src = edge_index[e];
  int dst = edge_index[(size_t)E + e];

  __shared__ float lw[4][112], lx[4][80], lcp[4][240];
  // x = s[src] + d[dst]
  {
    const float* srow = sbuf + (size_t)src * 80;
    const float* drow = dbuf + (size_t)dst * 80;
    for (int j = lane; j < 80; j += 64) lx[wave][j] = srow[j] + drow[j];
  }
  __syncthreads();
  build_cp(e, lane, rbf, rsh, W_rbf, lx[wave], lw[wave], lcp[wave]);

  // logit[h] = SCALE * sum_j qk[src][h][j] * cp[j]
  int hh = lane & 7, r = lane >> 3;
  const float* qk = qkbuf + (size_t)src * 1920 + hh * 240 + r * 30;
  const float* cp = lcp[wave] + r * 30;
  float acc = 0.f;
#pragma unroll
  for (int i = 0; i < 30; i++) acc += qk[i] * cp[i];
  acc += __shfl_xor(acc, 8);
  acc += __shfl_xor(acc, 16);
  acc += __shfl_xor(acc, 32);
  if (r == 0 && eraw < E) logits[(size_t)e * 8 + hh] = acc * SCALE_ATT;
}

// ---------------- per-node: softmax + a*cp aggregation + value GEMM + out ----------------
__global__ __launch_bounds__(64) void node_agg(
    const float* __restrict__ node,
    const float* __restrict__ rbf, const float* __restrict__ rsh,
    const int* __restrict__ edge_index,
    const float* __restrict__ W_rbf, const float* __restrict__ Wkv0,
    const float* __restrict__ Wkv1,
    const float* __restrict__ Wmsg0, const float* __restrict__ Wmsg1,
    const float* __restrict__ sbuf, const float* __restrict__ dbuf,
    const float* __restrict__ logits,
    const unsigned* __restrict__ offs, const unsigned* __restrict__ sorted,
    float* __restrict__ out, int N, int E) {
  int nidx = blockIdx.x;
  if (nidx >= N) return;
  int lane = threadIdx.x;
  int hh = lane & 7, r = lane >> 3;

  __shared__ float xd[80];     // d[dst=n]
  __shared__ float xbuf[80];   // s[src]+d[n] per edge
  __shared__ float wbuf[112];
  __shared__ float cpL[240];
  __shared__ float aL[8];
  __shared__ float zL[8];
  __shared__ float acpL[1920];
  __shared__ float mlL[640];

  unsigned off = offs[nidx];
  int deg = (int)(offs[nidx + 1] - off);

  for (int j = lane; j < 80; j += 64) xd[j] = dbuf[(size_t)nidx * 80 + j];

  // pass 1: per-head max over this node's incoming logits
  float mx = -3.4e38f;
  for (int i = lane; i < deg * 8; i += 64) {
    int t = i >> 3;
    unsigned e = sorted[off + t];
    mx = fmaxf(mx, logits[(size_t)e * 8 + (i & 7)]);
  }
  mx = fmaxf(mx, __shfl_xor(mx, 8));
  mx = fmaxf(mx, __shfl_xor(mx, 16));
  mx = fmaxf(mx, __shfl_xor(mx, 32));   // lane now holds max for h = lane&7

  // pass 2: accumulate acp[h][j] = sum_e a[e,h] * cp[e][j] in registers
  float acc[30];
#pragma unroll
  for (int i = 0; i < 30; i++) acc[i] = 0.f;
  float zreg = 0.f;
  __syncthreads();

  for (int t = 0; t < deg; ++t) {
    unsigned e = sorted[off + t];
    int src = edge_index[e];
    const float* srow = sbuf + (size_t)src * 80;
    for (int j = lane; j < 80; j += 64) xbuf[j] = srow[j] + xd[j];
    __syncthreads();
    build_cp((int)e, lane, rbf, rsh, W_rbf, xbuf, wbuf, cpL);
    if (r == 0) {
      float a = expf(logits[(size_t)e * 8 + hh] - mx);
      aL[hh] = a;
      zreg += a;
    }
    __syncthreads();
    float al = aL[hh];
    const float* cp = cpL + r * 30;
#pragma unroll
    for (int i = 0; i < 30; i++) acc[i] += al * cp[i];
    __syncthreads();  // protect LDS overwrite next iteration
  }

  // stage acp + z to LDS
#pragma unroll
  for (int i = 0; i < 30; i++) acpL[hh * 240 + r * 30 + i] = acc[i];
  if (r == 0) zL[hh] = zreg;
  __syncthreads();

  // value GEMM: ml[h][m] = (acp[h] . Wkv_val) / (z[h]+1e-16)
  for (int i = lane; i < 640; i += 64) {
    int h2 = i / 80, m = i % 80;
    float a2 = 0.f, val;
    const float* acp = acpL + h2 * 240;
    if (m < 32) {
      int col = 256 + h2 * 32 + m;
#pragma unroll
      for (int k = 0; k < 48; k++) a2 += acp[k] * Wkv0[(size_t)k * 512 + col];
      val = a2 * INV_SQRT48;
    } else {
      int mm = m - 32; int t = mm / 3, c = mm - t * 3;
      int col = 128 + h2 * 16 + t;
#pragma unroll
      for (int u = 0; u < 64; u++) a2 += acp[48 + u * 3 + c] * Wkv1[(size_t)u * 256 + col];
      val = a2 * 0.125f;
    }
    mlL[i] = val / (zL[h2] + 1e-16f);
  }
  __syncthreads();

  // output projection + residual
  const float* nrow = node + (size_t)nidx * 160;
  float* orow = out + (size_t)nidx * 160;
  {
    float a2 = 0.f;
    for (int j = 0; j < 256; j++) {
      int h2 = j >> 5, m = j & 31;
      a2 += mlL[h2 * 80 + m] * Wmsg0[(size_t)j * 64 + lane];
    }
    orow[lane] = nrow[lane] + a2 * 0.0625f;
  }
  for (int i = lane; i < 96; i += 64) {
    int v = i / 3, c = i - v * 3;
    float a2 = 0.f;
    for (int p = 0; p < 128; p++) {
      int h2 = p >> 4, t = p & 15;
      a2 += mlL[h2 * 80 + 32 + t * 3 + c] * Wmsg1[(size_t)p * 32 + v];
    }
    orow[64 + i] = nrow[64 + i] + a2 * INV_SQRT128;
  }
}

extern "C" void kernel_launch(void* const* d_in, const int* in_sizes, int n_in,
                              void* d_out, int out_size, void* d_ws, size_t ws_size,
                              hipStream_t stream) {
  (void)n_in; (void)out_size; (void)ws_size;
  const float* node   = (const float*)d_in[0];
  const float* rbf    = (const float*)d_in[1];
  const float* rsh    = (const float*)d_in[2];
  const int*   eidx   = (const int*)d_in[3];
  const float* gamma0 = (const float*)d_in[4];
  const float* gamma1 = (const float*)d_in[5];
  const float* Wq0    = (const float*)d_in[6];
  const float* Wq1    = (const float*)d_in[7];
  const float* Wsrc0  = (const float*)d_in[8];
  const float* Wsrc1  = (const float*)d_in[9];
  const float* Wdst0  = (const float*)d_in[10];
  const float* Wdst1  = (const float*)d_in[11];
  const float* W_rbf  = (const float*)d_in[12];
  const float* Wkv0   = (const float*)d_in[13];
  const float* Wkv1   = (const float*)d_in[14];
  const float* Wmsg0  = (const float*)d_in[15];
  const float* Wmsg1  = (const float*)d_in[16];
  float* out = (float*)d_out;

  int N = in_sizes[0] / 160;
  int E = in_sizes[3] / 2;

  float* sbuf   = (float*)d_ws;                          // N*80
  float* dbuf   = sbuf + (size_t)N * 80;                 // N*80
  float* qkbuf  = dbuf + (size_t)N * 80;                 // N*1920
  float* logits = qkbuf + (size_t)N * 1920;              // E*8
  unsigned* count  = (unsigned*)(logits + (size_t)E * 8);  // N
  unsigned* offs   = count + N;                            // N+1
  unsigned* cursor = offs + N + 1;                         // N
  unsigned* sorted = cursor + N;                           // E

  hipLaunchKernelGGL(init_count, dim3((N + 255) / 256), dim3(256), 0, stream, count, N);
  hipLaunchKernelGGL(node_pre, dim3(N), dim3(64), 0, stream,
                     node, gamma0, gamma1, Wq0, Wq1, Wsrc0, Wsrc1, Wdst0, Wdst1,
                     Wkv0, Wkv1, qkbuf, sbuf, dbuf, N);
  hipLaunchKernelGGL(k_hist, dim3((E + 255) / 256), dim3(256), 0, stream, eidx, count, E);
  hipLaunchKernelGGL(k_scan, dim3(1), dim3(256), 0, stream, count, offs, cursor, N);
  hipLaunchKernelGGL(k_scatter, dim3((E + 255) / 256), dim3(256), 0, stream,
                     eidx, cursor, sorted, E);
  hipLaunchKernelGGL(edge_logit, dim3((E + 3) / 4), dim3(256), 0, stream,
                     rbf, rsh, eidx, W_rbf, qkbuf, sbuf, dbuf, logits, E);
  hipLaunchKernelGGL(node_agg, dim3(N), dim3(64), 0, stream,
                     node, rbf, rsh, eidx, W_rbf, Wkv0, Wkv1, Wmsg0, Wmsg1,
                     sbuf, dbuf, logits, offs, sorted, out, N, E);
}